// Round 4
// baseline (489.037 us; speedup 1.0000x reference)
//
#include <hip/hip_runtime.h>
#include <hip/hip_bf16.h>
#include <math.h>

#define Hdim 512
#define Bdim 32
#define Sdim 2048
#define Kdim 1024            // 2*H
#define Mtot (Bdim * Sdim)   // 65536 rows

// scores GEMM tiling
#define BM 128
#define BN 128
#define BK 64                // 8 chunks of 8 bf16 per row (128 B lines)

typedef __attribute__((ext_vector_type(8))) short short8;
typedef __attribute__((ext_vector_type(4))) float floatx4;

// ---------------- fp32 -> bf16 (RNE) ----------------------------------------
__device__ __forceinline__ short f2bf(float f) {
    union { float f; unsigned u; } v; v.f = f;
    unsigned r = v.u + 0x7fffu + ((v.u >> 16) & 1u);
    return (short)(r >> 16);
}

// 8 fp32 -> 8 bf16 via packed converts (v_cvt_pk_bf16_f32 on gfx950)
__device__ __forceinline__ short8 cvt8(float4 a, float4 b) {
    union { short8 s; __hip_bfloat162 h[4]; } u;
    u.h[0] = __float22bfloat162_rn(make_float2(a.x, a.y));
    u.h[1] = __float22bfloat162_rn(make_float2(a.z, a.w));
    u.h[2] = __float22bfloat162_rn(make_float2(b.x, b.y));
    u.h[3] = __float22bfloat162_rn(make_float2(b.z, b.w));
    return u.s;
}

__device__ __forceinline__ float fast_tanh(float x) {
    float ax = fabsf(x);
    float e  = __expf(-2.0f * ax);
    float r  = (1.0f - e) / (1.0f + e);
    return copysignf(r, x);
}

// ---------------- Kernel 0: prep = conv_W (blocks 0..511) + dec_proj --------
__global__ __launch_bounds__(256) void prep_kernel(
    const float* __restrict__ W_attn, const float* __restrict__ dec,
    const float* __restrict__ b_attn, short* __restrict__ Wb,
    float* __restrict__ dec_proj)
{
    const int t = threadIdx.x;
    if (blockIdx.x < 512) {
        // W_e fp32 [k][n] -> bf16 [n][k] transpose
        const float* We = W_attn + Hdim * Hdim;   // [1024][512]
        __shared__ short tile[32][33];
        const int k0 = (blockIdx.x >> 4) * 32;
        const int n0 = (blockIdx.x & 15) * 32;
        const int r = t >> 5, c = t & 31;
        #pragma unroll
        for (int rr = 0; rr < 4; ++rr)
            tile[r + rr * 8][c] = f2bf(We[(size_t)(k0 + r + rr * 8) * Hdim + n0 + c]);
        __syncthreads();
        #pragma unroll
        for (int rr = 0; rr < 4; ++rr)
            Wb[(size_t)(n0 + r + rr * 8) * Kdim + k0 + c] = tile[c][r + rr * 8];
    } else {
        // dec_proj = decoder_hide @ W_h + b_attn
        __shared__ float partl[2][128];
        const int bid = blockIdx.x - 512;      // 0..127
        const int b  = bid >> 2;
        const int cb = bid & 3;
        const int c  = cb * 128 + (t & 127);
        const int kh = t >> 7;
        float acc = 0.0f;
        const int kbeg = kh * 256, kend = kbeg + 256;
        #pragma unroll 8
        for (int k = kbeg; k < kend; ++k)
            acc = fmaf(dec[b * Hdim + k], W_attn[(size_t)k * Hdim + c], acc);
        partl[kh][t & 127] = acc;
        __syncthreads();
        if (t < 128)
            dec_proj[b * Hdim + cb * 128 + t] = partl[0][t] + partl[1][t] + b_attn[cb * 128 + t];
    }
}

// ---------------- Kernel 1: fused MFMA scores -------------------------------
// LDS layout: row = 128 B line (64 bf16 = 8 chunks of 16 B).
// Logical chunk q of row m stored at physical chunk p = q ^ (m&7)  -> all
// staging writes and frag reads hit the 32-bank b128 floor (2-way over 16).
__global__ __launch_bounds__(256, 3) void scores_kernel(
    const float* __restrict__ enc,      // [65536][1024] fp32
    const short* __restrict__ Wb,       // [512][1024] bf16 (n-major)
    const float* __restrict__ dec_proj, // [32][512]
    const float* __restrict__ v_w,      // [512]
    float* __restrict__ part)           // [4][65536]
{
    __shared__ __align__(16) short Asm[BM * BK];   // 16 KB
    __shared__ __align__(16) short Bsm[BN * BK];   // 16 KB
    __shared__ float redl[BM][2];                  // 1 KB

    const int t    = threadIdx.x;
    const int nblk = blockIdx.x & 3;
    const int mblk = blockIdx.x >> 2;
    const int row0 = mblk * BM;
    const int n0   = nblk * BN;
    const int b    = row0 / Sdim;

    const int w    = t >> 6;
    const int lane = t & 63;
    const int ln   = lane & 15;
    const int quad = lane >> 4;
    const int wr   = (w >> 1) * 64;
    const int wc   = (w & 1) * 64;

    // ---- A staging map: thread -> (row sm, k-half sh), writes 4 chunks ----
    const int sm  = t >> 1;
    const int sh  = t & 1;
    const int smx = sm & 7;
    const float* Ag = enc + (size_t)(row0 + sm) * Kdim + sh * 32;
    short* Aw = Asm + sm * BK;
    int awc[4];
    #pragma unroll
    for (int i = 0; i < 4; ++i) awc[i] = ((sh * 4 + i) ^ smx) * 8;

    // ---- B DMA per-lane global offsets (elements), r = 0..3 ----
    const int l3 = lane >> 3, l7 = lane & 7;
    int boff[4];
    #pragma unroll
    for (int r = 0; r < 4; ++r)
        boff[r] = (n0 + (w * 4 + r) * 8 + l3) * Kdim + ((l7 ^ l3) * 8);
    short* bbase = Bsm + w * 2048;     // wave-uniform LDS dest base

    // ---- frag read addresses ----
    const int lnx = ln & 7;
    int arow[4], brow[4];
    #pragma unroll
    for (int i = 0; i < 4; ++i) {
        arow[i] = (wr + i * 16 + ln) * BK;
        brow[i] = (wc + i * 16 + ln) * BK;
    }
    const int pf0 = ((0 * 4 + quad) ^ lnx) * 8;
    const int pf1 = ((1 * 4 + quad) ^ lnx) * 8;

    floatx4 acc[4][4];
    #pragma unroll
    for (int i = 0; i < 4; ++i)
        #pragma unroll
        for (int j = 0; j < 4; ++j)
            acc[i][j] = (floatx4)(0.0f);

    for (int kt = 0; kt < Kdim; kt += BK) {
        __syncthreads();   // previous tile's frag reads complete
        // ---- B: async DMA global -> LDS (4 x 1 KB per wave) ----
        #pragma unroll
        for (int r = 0; r < 4; ++r) {
            const short* gp = Wb + boff[r] + kt;
            __builtin_amdgcn_global_load_lds(
                (const __attribute__((address_space(1))) unsigned int*)(const void*)gp,
                (__attribute__((address_space(3))) unsigned int*)(void*)(bbase + r * 512),
                16, 0, 0);
        }
        // ---- A: 128 B fp32 -> 64 B bf16, swizzled conflict-free write ----
        {
            const float4* g = (const float4*)(Ag + kt);
            float4 f0 = g[0], f1 = g[1], f2 = g[2], f3 = g[3];
            float4 f4 = g[4], f5 = g[5], f6 = g[6], f7 = g[7];
            *(short8*)&Aw[awc[0]] = cvt8(f0, f1);
            *(short8*)&Aw[awc[1]] = cvt8(f2, f3);
            *(short8*)&Aw[awc[2]] = cvt8(f4, f5);
            *(short8*)&Aw[awc[3]] = cvt8(f6, f7);
        }
        __syncthreads();   // drains DMA (vmcnt) + LDS writes

        // ---- 2 k-phases x 16 MFMAs ----
        #pragma unroll
        for (int f = 0; f < 2; ++f) {
            const int pf = f ? pf1 : pf0;
            short8 af[4], bfr[4];
            #pragma unroll
            for (int i = 0; i < 4; ++i) af[i]  = *(const short8*)&Asm[arow[i] + pf];
            #pragma unroll
            for (int j = 0; j < 4; ++j) bfr[j] = *(const short8*)&Bsm[brow[j] + pf];
            #pragma unroll
            for (int i = 0; i < 4; ++i)
                #pragma unroll
                for (int j = 0; j < 4; ++j)
                    acc[i][j] = __builtin_amdgcn_mfma_f32_16x16x32_bf16(
                                    af[i], bfr[j], acc[i][j], 0, 0, 0);
        }
    }

    // ---- epilogue: +dec_proj, tanh, *v_w, reduce this block's 128 cols ----
    float dpv[4], vwv[4];
    #pragma unroll
    for (int j = 0; j < 4; ++j) {
        int col = n0 + wc + j * 16 + ln;
        dpv[j] = dec_proj[b * Hdim + col];
        vwv[j] = v_w[col];
    }
    #pragma unroll
    for (int i = 0; i < 4; ++i) {
        #pragma unroll
        for (int reg = 0; reg < 4; ++reg) {
            float s = 0.0f;
            #pragma unroll
            for (int j = 0; j < 4; ++j) {
                float x = acc[i][j][reg] + dpv[j];
                s = fmaf(vwv[j], fast_tanh(x), s);
            }
            s += __shfl_xor(s, 1, 64);
            s += __shfl_xor(s, 2, 64);
            s += __shfl_xor(s, 4, 64);
            s += __shfl_xor(s, 8, 64);
            if (ln == 0)
                redl[wr + i * 16 + quad * 4 + reg][w & 1] = s;
        }
    }
    __syncthreads();
    if (t < BM)
        part[(size_t)nblk * Mtot + row0 + t] = redl[t][0] + redl[t][1];
}

// ---------------- Kernel 2: sum partials + masked softmax -------------------
__global__ __launch_bounds__(256) void softmax_kernel(
    const float* __restrict__ part, const int* __restrict__ mask,
    float* __restrict__ out)
{
    __shared__ float sred[8];
    const int b = blockIdx.x;
    const int t = threadIdx.x;
    const int lane = t & 63;
    const int wid  = t >> 6;

    float x[8];
    float m = -1e30f;
    #pragma unroll
    for (int j = 0; j < 8; ++j) {
        int idx = b * Sdim + j * 256 + t;
        float v = part[idx] + part[Mtot + idx] + part[2 * Mtot + idx] + part[3 * Mtot + idx];
        if (mask[idx] == 0) v = -100000.0f;
        x[j] = v;
        m = fmaxf(m, v);
    }
    #pragma unroll
    for (int off = 32; off >= 1; off >>= 1)
        m = fmaxf(m, __shfl_xor(m, off, 64));
    if (lane == 0) sred[wid] = m;
    __syncthreads();
    m = fmaxf(fmaxf(sred[0], sred[1]), fmaxf(sred[2], sred[3]));

    float s = 0.0f;
    #pragma unroll
    for (int j = 0; j < 8; ++j) {
        float e = __expf(x[j] - m);
        x[j] = e;
        s += e;
    }
    #pragma unroll
    for (int off = 32; off >= 1; off >>= 1)
        s += __shfl_xor(s, off, 64);
    if (lane == 0) sred[4 + wid] = s;
    __syncthreads();
    s = sred[4] + sred[5] + sred[6] + sred[7];

    const float inv = 1.0f / s;
    #pragma unroll
    for (int j = 0; j < 8; ++j)
        out[b * Sdim + j * 256 + t] = x[j] * inv;
}

// ---------------- launch ----------------------------------------------------
extern "C" void kernel_launch(void* const* d_in, const int* in_sizes, int n_in,
                              void* d_out, int out_size, void* d_ws, size_t ws_size,
                              hipStream_t stream) {
    const float* dec  = (const float*)d_in[0];   // (B, H)
    const float* enc  = (const float*)d_in[1];   // (B, S, 2H)
    const int*   mask = (const int*)  d_in[2];   // (B, S)
    const float* W    = (const float*)d_in[3];   // (3H, H)
    const float* ba   = (const float*)d_in[4];   // (H,)
    const float* vw   = (const float*)d_in[5];   // (H,)
    float* out = (float*)d_out;                  // (B, S)

    // workspace layout (~2.2 MB)
    float* dec_proj = (float*)d_ws;                       // 32*512 f   = 64 KB
    short* Wb       = (short*)(dec_proj + Bdim * Hdim);   // 512*1024 s = 1 MB
    float* part     = (float*)(Wb + Hdim * Kdim);         // 4*65536 f  = 1 MB

    prep_kernel<<<640, 256, 0, stream>>>(W, dec, ba, Wb, dec_proj);
    scores_kernel<<<(Mtot / BM) * 4, 256, 0, stream>>>(enc, Wb, dec_proj, vw, part);
    softmax_kernel<<<Bdim, 256, 0, stream>>>(part, mask, out);
}

// Round 5
// 429.866 us; speedup vs baseline: 1.1377x; 1.1377x over previous
//
#include <hip/hip_runtime.h>
#include <hip/hip_bf16.h>
#include <math.h>

#define Hdim 512
#define Bdim 32
#define Sdim 2048
#define Kdim 1024            // 2*H
#define Mtot (Bdim * Sdim)   // 65536 rows

// scores GEMM tiling: block = 64 rows x ALL 512 cols; wave w owns cols [128w,128w+128)
#define BM 64
#define BN 512
#define BK 64                // 8 chunks of 8 bf16 per 128 B LDS row

typedef __attribute__((ext_vector_type(8))) short short8;
typedef __attribute__((ext_vector_type(4))) float floatx4;

// ---------------- fp32 -> bf16 (RNE) ----------------------------------------
__device__ __forceinline__ short f2bf(float f) {
    union { float f; unsigned u; } v; v.f = f;
    unsigned r = v.u + 0x7fffu + ((v.u >> 16) & 1u);
    return (short)(r >> 16);
}

// 8 fp32 -> 8 bf16 via packed converts
__device__ __forceinline__ short8 cvt8(float4 a, float4 b) {
    union { short8 s; __hip_bfloat162 h[4]; } u;
    u.h[0] = __float22bfloat162_rn(make_float2(a.x, a.y));
    u.h[1] = __float22bfloat162_rn(make_float2(a.z, a.w));
    u.h[2] = __float22bfloat162_rn(make_float2(b.x, b.y));
    u.h[3] = __float22bfloat162_rn(make_float2(b.z, b.w));
    return u.s;
}

__device__ __forceinline__ float fast_tanh(float x) {
    float ax = fabsf(x);
    float e  = __expf(-2.0f * ax);
    float r  = (1.0f - e) * __builtin_amdgcn_rcpf(1.0f + e);
    return copysignf(r, x);
}

// ---------------- Kernel 0: prep = conv_W (blocks 0..511) + dec_proj --------
__global__ __launch_bounds__(256) void prep_kernel(
    const float* __restrict__ W_attn, const float* __restrict__ dec,
    const float* __restrict__ b_attn, short* __restrict__ Wb,
    float* __restrict__ dec_proj)
{
    const int t = threadIdx.x;
    if (blockIdx.x < 512) {
        // W_e fp32 [k][n] -> bf16 [n][k] transpose
        const float* We = W_attn + Hdim * Hdim;   // [1024][512]
        __shared__ short tile[32][33];
        const int k0 = (blockIdx.x >> 4) * 32;
        const int n0 = (blockIdx.x & 15) * 32;
        const int r = t >> 5, c = t & 31;
        #pragma unroll
        for (int rr = 0; rr < 4; ++rr)
            tile[r + rr * 8][c] = f2bf(We[(size_t)(k0 + r + rr * 8) * Hdim + n0 + c]);
        __syncthreads();
        #pragma unroll
        for (int rr = 0; rr < 4; ++rr)
            Wb[(size_t)(n0 + r + rr * 8) * Kdim + k0 + c] = tile[c][r + rr * 8];
    } else {
        // dec_proj = decoder_hide @ W_h + b_attn
        __shared__ float partl[2][128];
        const int bid = blockIdx.x - 512;      // 0..127
        const int b  = bid >> 2;
        const int cb = bid & 3;
        const int c  = cb * 128 + (t & 127);
        const int kh = t >> 7;
        float acc = 0.0f;
        const int kbeg = kh * 256, kend = kbeg + 256;
        #pragma unroll 8
        for (int k = kbeg; k < kend; ++k)
            acc = fmaf(dec[b * Hdim + k], W_attn[(size_t)k * Hdim + c], acc);
        partl[kh][t & 127] = acc;
        __syncthreads();
        if (t < 128)
            dec_proj[b * Hdim + cb * 128 + t] = partl[0][t] + partl[1][t] + b_attn[cb * 128 + t];
    }
}

// ---------------- Kernel 1: fused MFMA scores, full-N per block -------------
// LDS rows are 128 B (64 bf16 = 8 chunks of 16 B); logical chunk q of row m
// stored at physical p = q ^ (m&7) -> conflict-free writes + frag reads (R4-verified).
__global__ __launch_bounds__(256, 2) void scores_kernel(
    const float* __restrict__ enc,      // [65536][1024] fp32
    const short* __restrict__ Wb,       // [512][1024] bf16 (n-major)
    const float* __restrict__ dec_proj, // [32][512]
    const float* __restrict__ v_w,      // [512]
    float* __restrict__ scores)         // [65536]
{
    __shared__ __align__(16) short Asm[BM * BK];   // 8 KB
    __shared__ __align__(16) short Bsm[BN * BK];   // 64 KB
    __shared__ float redl[BM][4];                  // 1 KB

    const int t    = threadIdx.x;
    const int row0 = blockIdx.x * BM;
    const int b    = row0 / Sdim;        // 32 m-blocks per batch -> uniform

    const int w    = t >> 6;             // wave 0..3 -> n-slice [128w, 128w+128)
    const int lane = t & 63;
    const int ln   = lane & 15;
    const int quad = lane >> 4;

    // ---- A staging map: thread -> (row sm, quarter sq of 16 fp32) ----
    const int sm = t >> 2;               // 0..63
    const int sq = t & 3;
    const float* Ag = enc + (size_t)(row0 + sm) * Kdim + sq * 16;
    short* Aw = Asm + sm * BK;
    const int aw0 = ((2 * sq)     ^ (sm & 7)) * 8;
    const int aw1 = ((2 * sq + 1) ^ (sm & 7)) * 8;

    // ---- B DMA: wave w stages its own 128 n-rows (16 issues of 8 rows) ----
    const int l3 = lane >> 3, l7 = lane & 7;
    const short* Bg0 = Wb + (size_t)(w * 128 + l3) * Kdim + ((l7 ^ l3) * 8);

    // ---- frag read addresses ----
    int arow[4], brow[8];
    #pragma unroll
    for (int i = 0; i < 4; ++i) arow[i] = (i * 16 + ln) * BK;
    #pragma unroll
    for (int j = 0; j < 8; ++j) brow[j] = (w * 128 + j * 16 + ln) * BK;
    const int pf0 = (quad       ^ (ln & 7)) * 8;   // k-phase 0 chunks 0..3
    const int pf1 = ((4 + quad) ^ (ln & 7)) * 8;   // k-phase 1 chunks 4..7

    floatx4 acc[4][8];
    #pragma unroll
    for (int i = 0; i < 4; ++i)
        #pragma unroll
        for (int j = 0; j < 8; ++j)
            acc[i][j] = (floatx4)(0.0f);

    for (int kt = 0; kt < Kdim; kt += BK) {
        __syncthreads();   // previous tile's frag reads complete
        // ---- B: async DMA global -> LDS, 16 KB per wave ----
        #pragma unroll
        for (int r = 0; r < 16; ++r) {
            __builtin_amdgcn_global_load_lds(
                (const __attribute__((address_space(1))) unsigned int*)(const void*)
                    (Bg0 + (size_t)r * 8 * Kdim + kt),
                (__attribute__((address_space(3))) unsigned int*)(void*)
                    (Bsm + (w * 128 + r * 8) * BK),
                16, 0, 0);
        }
        // ---- A: 64 B fp32 -> 32 B bf16 per thread, swizzled write ----
        {
            const float4* g = (const float4*)(Ag + kt);
            float4 f0 = g[0], f1 = g[1], f2 = g[2], f3 = g[3];
            *(short8*)&Aw[aw0] = cvt8(f0, f1);
            *(short8*)&Aw[aw1] = cvt8(f2, f3);
        }
        __syncthreads();   // drains DMA + LDS writes

        // ---- 2 k-phases x (4 m-tiles x 8 n-tiles) MFMAs ----
        #pragma unroll
        for (int f = 0; f < 2; ++f) {
            const int pf = f ? pf1 : pf0;
            short8 af[4], bfr[8];
            #pragma unroll
            for (int i = 0; i < 4; ++i) af[i]  = *(const short8*)&Asm[arow[i] + pf];
            #pragma unroll
            for (int j = 0; j < 8; ++j) bfr[j] = *(const short8*)&Bsm[brow[j] + pf];
            #pragma unroll
            for (int i = 0; i < 4; ++i)
                #pragma unroll
                for (int j = 0; j < 8; ++j)
                    acc[i][j] = __builtin_amdgcn_mfma_f32_16x16x32_bf16(
                                    af[i], bfr[j], acc[i][j], 0, 0, 0);
        }
    }

    // ---- epilogue: +dec_proj, tanh, *v_w; each wave sums its 128 cols ----
    float dpv[8], vwv[8];
    #pragma unroll
    for (int j = 0; j < 8; ++j) {
        int col = w * 128 + j * 16 + ln;
        dpv[j] = dec_proj[b * Hdim + col];
        vwv[j] = v_w[col];
    }
    #pragma unroll
    for (int i = 0; i < 4; ++i) {
        #pragma unroll
        for (int reg = 0; reg < 4; ++reg) {
            float s = 0.0f;
            #pragma unroll
            for (int j = 0; j < 8; ++j) {
                float x = acc[i][j][reg] + dpv[j];
                s = fmaf(vwv[j], fast_tanh(x), s);
            }
            s += __shfl_xor(s, 1, 64);
            s += __shfl_xor(s, 2, 64);
            s += __shfl_xor(s, 4, 64);
            s += __shfl_xor(s, 8, 64);
            if (ln == 0)
                redl[i * 16 + quad * 4 + reg][w] = s;
        }
    }
    __syncthreads();
    if (t < BM)
        scores[row0 + t] = redl[t][0] + redl[t][1] + redl[t][2] + redl[t][3];
}

// ---------------- Kernel 2: masked softmax over S per batch -----------------
__global__ __launch_bounds__(256) void softmax_kernel(
    const float* __restrict__ scores, const int* __restrict__ mask,
    float* __restrict__ out)
{
    __shared__ float sred[8];
    const int b = blockIdx.x;
    const int t = threadIdx.x;
    const int lane = t & 63;
    const int wid  = t >> 6;

    float x[8];
    float m = -1e30f;
    #pragma unroll
    for (int j = 0; j < 8; ++j) {
        int idx = b * Sdim + j * 256 + t;
        float v = scores[idx];
        if (mask[idx] == 0) v = -100000.0f;
        x[j] = v;
        m = fmaxf(m, v);
    }
    #pragma unroll
    for (int off = 32; off >= 1; off >>= 1)
        m = fmaxf(m, __shfl_xor(m, off, 64));
    if (lane == 0) sred[wid] = m;
    __syncthreads();
    m = fmaxf(fmaxf(sred[0], sred[1]), fmaxf(sred[2], sred[3]));

    float s = 0.0f;
    #pragma unroll
    for (int j = 0; j < 8; ++j) {
        float e = __expf(x[j] - m);
        x[j] = e;
        s += e;
    }
    #pragma unroll
    for (int off = 32; off >= 1; off >>= 1)
        s += __shfl_xor(s, off, 64);
    if (lane == 0) sred[4 + wid] = s;
    __syncthreads();
    s = sred[4] + sred[5] + sred[6] + sred[7];

    const float inv = 1.0f / s;
    #pragma unroll
    for (int j = 0; j < 8; ++j)
        out[b * Sdim + j * 256 + t] = x[j] * inv;
}

// ---------------- launch ----------------------------------------------------
extern "C" void kernel_launch(void* const* d_in, const int* in_sizes, int n_in,
                              void* d_out, int out_size, void* d_ws, size_t ws_size,
                              hipStream_t stream) {
    const float* dec  = (const float*)d_in[0];   // (B, H)
    const float* enc  = (const float*)d_in[1];   // (B, S, 2H)
    const int*   mask = (const int*)  d_in[2];   // (B, S)
    const float* W    = (const float*)d_in[3];   // (3H, H)
    const float* ba   = (const float*)d_in[4];   // (H,)
    const float* vw   = (const float*)d_in[5];   // (H,)
    float* out = (float*)d_out;                  // (B, S)

    // workspace layout (~1.3 MB)
    float* dec_proj = (float*)d_ws;                       // 32*512 f   = 64 KB
    short* Wb       = (short*)(dec_proj + Bdim * Hdim);   // 512*1024 s = 1 MB
    float* scores   = (float*)(Wb + Hdim * Kdim);         // 65536 f    = 256 KB

    prep_kernel<<<640, 256, 0, stream>>>(W, dec, ba, Wb, dec_proj);
    scores_kernel<<<Mtot / BM, 256, 0, stream>>>(enc, Wb, dec_proj, vw, scores);
    softmax_kernel<<<Bdim, 256, 0, stream>>>(scores, mask, out);
}